// Round 1
// baseline (289.220 us; speedup 1.0000x reference)
//
#include <hip/hip_runtime.h>

// Problem constants from the reference
constexpr int B_ = 32;
constexpr int S_ = 2048;
constexpr int F_ = 512;
constexpr int ROWS = B_ * S_;          // 65536 rows of length F=512
constexpr int WAVES_PER_BLOCK = 4;     // 256 threads
constexpr int ROWS_PER_WAVE = 2;       // R6: 2 rows/wave -> 8 loads in flight

typedef float f32x4 __attribute__((ext_vector_type(4)));

// out = one_hot(argmax_F(logits + gumbel)) per row.  (Reference's
// softmax/straight-through/top_k/scatter pipeline is the identity on the
// hard one-hot: non-argmax entries are exactly +0.0, and top_k(-mask, K)
// selects only already-zero entries since K < #zeros per sample.)
//
// R5: split into a READ-ONLY phase and a WRITE-ONLY phase (mixed 2:1
// read:write measured 3.56 TB/s effective vs ~6.7 TB/s unidirectional).
// R6: phase-1 MLP polish. Each wave owns 2 rows and issues all 8
// nontemporal f32x4 loads before any dependent math, doubling the
// outstanding-load depth per wave (4 KB -> 8 KB in flight) and halving
// per-row wave/block overhead. Reduce/ballot logic per row unchanged.
// Phase 2 byte-identical to the verified R5 version (already at fill rate).

__global__ __launch_bounds__(256) void argmax_phase_kernel(
    const float* __restrict__ logits,
    const float* __restrict__ gumbel,
    int* __restrict__ row_idx)
{
    const int lane = threadIdx.x & 63;
    const int wave = threadIdx.x >> 6;
    const int wrow = (blockIdx.x * WAVES_PER_BLOCK + wave) * ROWS_PER_WAVE;

    // Issue all 8 independent 16B NT loads up front (read-once streams:
    // don't let L3 fills evict unread input lines; 268 MB inputs > 256 MB L3).
    f32x4 a[ROWS_PER_WAVE][2], g[ROWS_PER_WAVE][2];
#pragma unroll
    for (int r = 0; r < ROWS_PER_WAVE; ++r) {
        const size_t off = (size_t)(wrow + r) * F_;
        const f32x4* __restrict__ lg = (const f32x4*)(logits + off);
        const f32x4* __restrict__ gm = (const f32x4*)(gumbel + off);
        a[r][0] = __builtin_nontemporal_load(&lg[lane]);
        a[r][1] = __builtin_nontemporal_load(&lg[lane + 64]);
        g[r][0] = __builtin_nontemporal_load(&gm[lane]);
        g[r][1] = __builtin_nontemporal_load(&gm[lane + 64]);
    }

#pragma unroll
    for (int r = 0; r < ROWS_PER_WAVE; ++r) {
        // 512 floats / row = 128 f32x4. Lane i handles slots i and i+64.
        float v[8];
        v[0] = a[r][0].x + g[r][0].x; v[1] = a[r][0].y + g[r][0].y;
        v[2] = a[r][0].z + g[r][0].z; v[3] = a[r][0].w + g[r][0].w;
        v[4] = a[r][1].x + g[r][1].x; v[5] = a[r][1].y + g[r][1].y;
        v[6] = a[r][1].z + g[r][1].z; v[7] = a[r][1].w + g[r][1].w;

        // Local max of 8 (tree), then 6-step wave-wide max butterfly.
        float m01 = fmaxf(v[0], v[1]), m23 = fmaxf(v[2], v[3]);
        float m45 = fmaxf(v[4], v[5]), m67 = fmaxf(v[6], v[7]);
        float best = fmaxf(fmaxf(m01, m23), fmaxf(m45, m67));
#pragma unroll
        for (int off = 32; off > 0; off >>= 1)
            best = fmaxf(best, __shfl_xor(best, off, 64));
        // max is a selection -> best is exactly some v element; == finds it.

        // First-index argmax. Lane L holds global indices 4L..4L+3 (half0)
        // and 256+4L..4L+3 (half1); all of half0 precedes half1.
        int j0 = 4, j1 = 4;
#pragma unroll
        for (int j = 3; j >= 0; --j) {
            if (v[j] == best)     j0 = j;
            if (v[4 + j] == best) j1 = j;
        }
        unsigned long long bal0 = __ballot(j0 < 4);
        unsigned long long bal1 = __ballot(j1 < 4);
        int cand0 = 4 * lane + j0;
        int cand1 = 256 + 4 * lane + j1;

        int idx;
        if (bal0) {
            idx = __shfl(cand0, __builtin_ctzll(bal0), 64);
        } else {
            idx = __shfl(cand1, __builtin_ctzll(bal1), 64);
        }

        if (lane == 0) row_idx[wrow + r] = idx;
    }
}

// Pure streaming write: each thread emits two f32x4 (32 B), grid-stride by
// half the slot count so both passes are fully coalesced.
constexpr int F4_PER_ROW   = F_ / 4;                 // 128
constexpr size_t TOTAL_F4  = (size_t)ROWS * F4_PER_ROW;   // 8388608
constexpr int K2_BLOCKS    = (int)(TOTAL_F4 / 2 / 256);   // 16384

__global__ __launch_bounds__(256) void onehot_phase_kernel(
    const int* __restrict__ row_idx,
    float* __restrict__ out)
{
    const size_t tid = (size_t)blockIdx.x * 256 + threadIdx.x;
    f32x4* __restrict__ op = (f32x4*)out;

#pragma unroll
    for (int p = 0; p < 2; ++p) {
        const size_t slot = tid + (size_t)p * (TOTAL_F4 / 2);
        const int row  = (int)(slot >> 7);           // 128 f4 per row
        const int ebase = ((int)slot & 127) * 4;     // element index of .x
        const int idx = row_idx[row];                // L2-hit broadcast

        f32x4 z;
        z.x = (ebase + 0 == idx) ? 1.0f : 0.0f;
        z.y = (ebase + 1 == idx) ? 1.0f : 0.0f;
        z.z = (ebase + 2 == idx) ? 1.0f : 0.0f;
        z.w = (ebase + 3 == idx) ? 1.0f : 0.0f;
        op[slot] = z;
    }
}

extern "C" void kernel_launch(void* const* d_in, const int* in_sizes, int n_in,
                              void* d_out, int out_size, void* d_ws, size_t ws_size,
                              hipStream_t stream) {
    const float* logits = (const float*)d_in[0];
    const float* gumbel = (const float*)d_in[1];
    float* out = (float*)d_out;
    int* row_idx = (int*)d_ws;   // 65536 * 4 B = 256 KB of workspace

    const int grid1 = ROWS / (WAVES_PER_BLOCK * ROWS_PER_WAVE);  // 8192 blocks
    argmax_phase_kernel<<<grid1, 256, 0, stream>>>(logits, gumbel, row_idx);
    onehot_phase_kernel<<<K2_BLOCKS, 256, 0, stream>>>(row_idx, out);
}